// Round 1
// baseline (1595.396 us; speedup 1.0000x reference)
//
#include <hip/hip_runtime.h>
#include <hip/hip_bf16.h>

typedef __attribute__((ext_vector_type(8))) short short8;
typedef __attribute__((ext_vector_type(4))) float f32x4;
typedef __attribute__((ext_vector_type(4))) unsigned int uint4v;

#define BM 128
#define BN 128
#define BK 64

// async global->LDS, 16B per lane. LDS dest must be wave-uniform base + lane*16.
__device__ __forceinline__ void gl_lds16(const __hip_bfloat16* g, __hip_bfloat16* l) {
  __builtin_amdgcn_global_load_lds((const __attribute__((address_space(1))) void*)g,
                                   (__attribute__((address_space(3))) void*)l,
                                   16, 0, 0);
}

// Dequantize qweight [in_f/8, out_f] int4-packed -> W^T bf16 [out_f, in_f].
// Each thread: fixed n, a chunk of 64 k (8 packed int32 rows) -> 128B contiguous store.
__global__ void dequant_kernel(const int* __restrict__ qweight,
                               const int* __restrict__ qzeros,
                               const float* __restrict__ scales,
                               const int* __restrict__ g_idx,
                               __hip_bfloat16* __restrict__ wt,
                               int in_f, int out_f) {
  const int n = blockIdx.x * blockDim.x + threadIdx.x;
  if (n >= out_f) return;
  const int kc = blockIdx.y;               // chunk of 64 k values
  const int g = g_idx[kc * 64];            // group constant within chunk (128 | 64*kc alignment)
  const float s = scales[(size_t)g * out_f + n];
  const int zq = qzeros[(size_t)g * (out_f >> 3) + (n >> 3)];
  const float z = (float)((zq >> ((n & 7) * 4)) & 15);
  const float c = s * z;
  __hip_bfloat16* dst = wt + (size_t)n * in_f + kc * 64;
  for (int u = 0; u < 8; u++) {
    const int q = qweight[(size_t)(kc * 8 + u) * out_f + n];
    __hip_bfloat16 v[8];
#pragma unroll
    for (int j = 0; j < 8; j++) {
      const float w = (float)((q >> (4 * j)) & 15);
      v[j] = __float2bfloat16(fmaf(s, w, -c));
    }
    *(uint4v*)(dst + u * 8) = *(const uint4v*)v;
  }
}

// x fp32 -> bf16, 8 elements per thread.
__global__ void cvtx_kernel(const float* __restrict__ x,
                            __hip_bfloat16* __restrict__ xb, size_t n8) {
  const size_t i = (size_t)blockIdx.x * blockDim.x + threadIdx.x;
  if (i >= n8) return;
  const float4* p = (const float4*)x + i * 2;
  const float4 a = p[0];
  const float4 b = p[1];
  __hip_bfloat16 v[8];
  v[0] = __float2bfloat16(a.x); v[1] = __float2bfloat16(a.y);
  v[2] = __float2bfloat16(a.z); v[3] = __float2bfloat16(a.w);
  v[4] = __float2bfloat16(b.x); v[5] = __float2bfloat16(b.y);
  v[6] = __float2bfloat16(b.z); v[7] = __float2bfloat16(b.w);
  ((uint4v*)xb)[i] = *(const uint4v*)v;
}

// m97-structure bf16 GEMM: C[M,N] = A[M,K] * Bt[N,K]^T + bias
// 128x128 tile / block (256 thr, 4 waves), BK=64, 16x16x32 MFMA, 4x4 frags/wave.
__global__ __launch_bounds__(256) void gemm_kernel(
    const __hip_bfloat16* __restrict__ A,
    const __hip_bfloat16* __restrict__ Bt,
    const float* __restrict__ bias,
    float* __restrict__ C, int M, int N, int K) {
  __shared__ __hip_bfloat16 As[BM * BK];
  __shared__ __hip_bfloat16 Bs[BN * BK];
  const int tid = threadIdx.x;
  const int m0 = blockIdx.y * BM;
  const int n0 = blockIdx.x * BN;
  const int wv = tid >> 6, ln = tid & 63;
  const int wm = (wv & 1) * 64, wn = (wv >> 1) * 64;
  const int lr = ln & 15, lk = (ln >> 4) * 8;

  const __hip_bfloat16* Ab = A + (size_t)m0 * K;
  const __hip_bfloat16* Bb = Bt + (size_t)n0 * K;

  f32x4 acc[4][4] = {};

  for (int kt = 0; kt < K; kt += BK) {
#pragma unroll
    for (int i = 0; i < 4; i++) {
      const int id = i * 256 + tid;
      const int row = id >> 3, kc = (id & 7) * 8;
      gl_lds16(Ab + (size_t)row * K + kt + kc, &As[id * 8]);
    }
#pragma unroll
    for (int i = 0; i < 4; i++) {
      const int id = i * 256 + tid;
      const int row = id >> 3, kc = (id & 7) * 8;
      gl_lds16(Bb + (size_t)row * K + kt + kc, &Bs[id * 8]);
    }
    __syncthreads();  // drains vmcnt -> LDS tiles ready
#pragma unroll
    for (int ks = 0; ks < 2; ks++) {
      short8 af[4], bf[4];
#pragma unroll
      for (int mf = 0; mf < 4; mf++)
        af[mf] = *(const short8*)&As[(wm + mf * 16 + lr) * BK + ks * 32 + lk];
#pragma unroll
      for (int nf = 0; nf < 4; nf++)
        bf[nf] = *(const short8*)&Bs[(wn + nf * 16 + lr) * BK + ks * 32 + lk];
#pragma unroll
      for (int mf = 0; mf < 4; mf++)
#pragma unroll
        for (int nf = 0; nf < 4; nf++)
          acc[mf][nf] = __builtin_amdgcn_mfma_f32_16x16x32_bf16(
              af[mf], bf[nf], acc[mf][nf], 0, 0, 0);
    }
    __syncthreads();  // tile consumed before next overwrite
  }

  // C/D layout: col = lane&15, row = (lane>>4)*4 + reg   [m89/m91-verified]
  const int cr = m0 + wm + (ln >> 4) * 4;
  const int cc = n0 + wn + lr;
#pragma unroll
  for (int nf = 0; nf < 4; nf++) {
    const float bv = bias[cc + nf * 16];
#pragma unroll
    for (int mf = 0; mf < 4; mf++) {
#pragma unroll
      for (int r = 0; r < 4; r++) {
        C[(size_t)(cr + mf * 16 + r) * N + cc + nf * 16] = acc[mf][nf][r] + bv;
      }
    }
  }
}

// Correct-but-slow fallback if workspace is too small (diagnostic path).
__global__ void naive_kernel(const float* __restrict__ x, const int* __restrict__ qweight,
                             const int* __restrict__ qzeros, const float* __restrict__ scales,
                             const float* __restrict__ bias, const int* __restrict__ g_idx,
                             float* __restrict__ out, int in_f, int out_f) {
  const int n = blockIdx.x * blockDim.x + threadIdx.x;
  if (n >= out_f) return;
  const int m = blockIdx.y;
  const float* xr = x + (size_t)m * in_f;
  float acc = 0.f;
  for (int kk = 0; kk < (in_f >> 3); kk++) {
    const int q = qweight[(size_t)kk * out_f + n];
    const int g = g_idx[kk * 8];
    const float s = scales[(size_t)g * out_f + n];
    const int z = (qzeros[(size_t)g * (out_f >> 3) + (n >> 3)] >> ((n & 7) * 4)) & 15;
    float part = 0.f;
#pragma unroll
    for (int j = 0; j < 8; j++)
      part += xr[kk * 8 + j] * (float)(((q >> (4 * j)) & 15) - z);
    acc += s * part;
  }
  out[(size_t)m * out_f + n] = acc + bias[n];
}

extern "C" void kernel_launch(void* const* d_in, const int* in_sizes, int n_in,
                              void* d_out, int out_size, void* d_ws, size_t ws_size,
                              hipStream_t stream) {
  const float* x = (const float*)d_in[0];
  const int* qweight = (const int*)d_in[1];
  const int* qzeros = (const int*)d_in[2];
  const float* scales = (const float*)d_in[3];
  const float* bias = (const float*)d_in[4];
  const int* g_idx = (const int*)d_in[5];
  float* out = (float*)d_out;

  const int out_f = in_sizes[4];          // bias length
  const int in_f = in_sizes[5];           // g_idx length
  const int tokens = in_sizes[0] / in_f;  // x rows

  const size_t need_w = (size_t)in_f * out_f * sizeof(__hip_bfloat16);
  const size_t need_x = (size_t)tokens * in_f * sizeof(__hip_bfloat16);

  if (ws_size >= need_w + need_x && (in_f % BK) == 0 && (in_f % 128) == 0 &&
      (out_f % BN) == 0 && (tokens % BM) == 0) {
    __hip_bfloat16* wt = (__hip_bfloat16*)d_ws;
    __hip_bfloat16* xb = (__hip_bfloat16*)((char*)d_ws + need_w);
    dequant_kernel<<<dim3((out_f + 255) / 256, in_f / 64), 256, 0, stream>>>(
        qweight, qzeros, scales, g_idx, wt, in_f, out_f);
    const size_t n8 = (size_t)tokens * in_f / 8;
    cvtx_kernel<<<dim3((unsigned)((n8 + 255) / 256)), 256, 0, stream>>>(x, xb, n8);
    gemm_kernel<<<dim3(out_f / BN, tokens / BM), 256, 0, stream>>>(
        xb, wt, bias, out, tokens, out_f, in_f);
  } else {
    naive_kernel<<<dim3((out_f + 255) / 256, tokens), 256, 0, stream>>>(
        x, qweight, qzeros, scales, bias, g_idx, out, in_f, out_f);
  }
}

// Round 2
// 1432.980 us; speedup vs baseline: 1.1133x; 1.1133x over previous
//
#include <hip/hip_runtime.h>
#include <hip/hip_bf16.h>

typedef __attribute__((ext_vector_type(8))) short short8;
typedef __attribute__((ext_vector_type(4))) float f32x4;
typedef __attribute__((ext_vector_type(4))) unsigned int uint4v;

#define BM 128
#define BN 128
#define BK 64

// async global->LDS, 16B per lane. LDS dest must be wave-uniform base + lane*16.
__device__ __forceinline__ void gl_lds16(const __hip_bfloat16* g, __hip_bfloat16* l) {
  __builtin_amdgcn_global_load_lds((const __attribute__((address_space(1))) void*)g,
                                   (__attribute__((address_space(3))) void*)l,
                                   16, 0, 0);
}

// Dequant qweight [K/8, N] int4-packed -> W' in 16B-chunk layout: chunk (kc, n)
// = W^T[n][kc*8 .. kc*8+8) stored at chunk index kc*N + n.
// One thread = one chunk: 1 coalesced int read -> 1 coalesced 16B write.
__global__ void dequant_kernel(const int* __restrict__ qweight,
                               const int* __restrict__ qzeros,
                               const float* __restrict__ scales,
                               __hip_bfloat16* __restrict__ wp, int N, int K) {
  const int n = blockIdx.x * 256 + threadIdx.x;   // N % 256 == 0
  const int kc = blockIdx.y;                      // qweight row = k/8
  const int g = kc >> 4;                          // (kc*8)/128
  const float s = scales[(size_t)g * N + n];
  const int zq = qzeros[(size_t)g * (N >> 3) + (n >> 3)];
  const float c = s * (float)((zq >> ((n & 7) * 4)) & 15);
  const int q = qweight[(size_t)kc * N + n];
  __hip_bfloat16 v[8];
#pragma unroll
  for (int j = 0; j < 8; j++)
    v[j] = __float2bfloat16(fmaf(s, (float)((q >> (4 * j)) & 15), -c));
  ((uint4v*)wp)[(size_t)kc * N + n] = *(const uint4v*)v;
}

// x fp32 [M,K] -> bf16 chunk layout X': chunk (kc, m) at index kc*M + m.
// 64m x 64k tile per block, LDS transpose so both sides are coalesced.
__global__ void cvtx_kernel(const float* __restrict__ x,
                            __hip_bfloat16* __restrict__ xp, int M, int K) {
  __shared__ __hip_bfloat16 tile[64 * 64];  // slot = c8*64 + m_local, 8 bf16/slot
  const int t = threadIdx.x;
  const int m0 = blockIdx.x * 64, k0 = blockIdx.y * 64;
  const int mr = t >> 2, cq = t & 3;  // 4 threads/row, 16 fp32 each
  const float4* src = (const float4*)(x + (size_t)(m0 + mr) * K + k0 + cq * 16);
  const float4 a = src[0], b = src[1], c = src[2], d = src[3];
  __hip_bfloat16 v[16];
  v[0] = __float2bfloat16(a.x);  v[1] = __float2bfloat16(a.y);
  v[2] = __float2bfloat16(a.z);  v[3] = __float2bfloat16(a.w);
  v[4] = __float2bfloat16(b.x);  v[5] = __float2bfloat16(b.y);
  v[6] = __float2bfloat16(b.z);  v[7] = __float2bfloat16(b.w);
  v[8] = __float2bfloat16(c.x);  v[9] = __float2bfloat16(c.y);
  v[10] = __float2bfloat16(c.z); v[11] = __float2bfloat16(c.w);
  v[12] = __float2bfloat16(d.x); v[13] = __float2bfloat16(d.y);
  v[14] = __float2bfloat16(d.z); v[15] = __float2bfloat16(d.w);
  *(uint4v*)&tile[((cq * 2 + 0) * 64 + mr) * 8] = *(const uint4v*)&v[0];
  *(uint4v*)&tile[((cq * 2 + 1) * 64 + mr) * 8] = *(const uint4v*)&v[8];
  __syncthreads();
#pragma unroll
  for (int j = 0; j < 2; j++) {
    const int s = j * 256 + t;
    const int c8 = s >> 6, m = s & 63;
    ((uint4v*)xp)[(size_t)((k0 >> 3) + c8) * M + m0 + m] = *(const uint4v*)&tile[s * 8];
  }
}

// bf16 GEMM on chunk-transposed operands: C[M,N] = X W^T + bias.
// LDS tiles chunk-major [c8][row] -> conflict-free ds_read_b128 and
// 1KB-contiguous global_load_lds staging per wave.
__global__ __launch_bounds__(256) void gemm_kernel(
    const __hip_bfloat16* __restrict__ Xp,  // chunks [K/8][M]
    const __hip_bfloat16* __restrict__ Wp,  // chunks [K/8][N]
    const float* __restrict__ bias,
    float* __restrict__ C, int M, int N, int K) {
  __shared__ __hip_bfloat16 As[BM * BK];  // slot = c8*128 + m_local
  __shared__ __hip_bfloat16 Bs[BN * BK];  // slot = c8*128 + n_local
  const int tid = threadIdx.x;
  const int m0 = blockIdx.x * BM;  // x fastest => consecutive blocks share n0
  const int n0 = blockIdx.y * BN;
  const int wv = tid >> 6, ln = tid & 63;
  const int wm = (wv & 1) * 64, wn = (wv >> 1) * 64;
  const int lr = ln & 15, q4 = ln >> 4;

  f32x4 acc[4][4] = {};

  const int K8 = K >> 3;
  for (int kt8 = 0; kt8 < K8; kt8 += 8) {
#pragma unroll
    for (int i = 0; i < 4; i++) {
      const int s = i * 256 + tid;
      const int c8 = s >> 7, ml = s & 127;
      gl_lds16(Xp + ((size_t)(kt8 + c8) * M + m0 + ml) * 8, &As[s * 8]);
    }
#pragma unroll
    for (int i = 0; i < 4; i++) {
      const int s = i * 256 + tid;
      const int c8 = s >> 7, nl = s & 127;
      gl_lds16(Wp + ((size_t)(kt8 + c8) * N + n0 + nl) * 8, &Bs[s * 8]);
    }
    __syncthreads();
#pragma unroll
    for (int ks = 0; ks < 2; ks++) {
      const int q = ks * 4 + q4;
      short8 af[4], bf[4];
#pragma unroll
      for (int mf = 0; mf < 4; mf++)
        af[mf] = *(const short8*)&As[q * 1024 + (wm + mf * 16 + lr) * 8];
#pragma unroll
      for (int nf = 0; nf < 4; nf++)
        bf[nf] = *(const short8*)&Bs[q * 1024 + (wn + nf * 16 + lr) * 8];
#pragma unroll
      for (int mf = 0; mf < 4; mf++)
#pragma unroll
        for (int nf = 0; nf < 4; nf++)
          acc[mf][nf] = __builtin_amdgcn_mfma_f32_16x16x32_bf16(
              af[mf], bf[nf], acc[mf][nf], 0, 0, 0);
    }
    __syncthreads();
  }

  // C/D layout: col = lane&15, row = (lane>>4)*4 + reg  [m89/m91-verified]
  const int cr = m0 + wm + q4 * 4;
  const int cc = n0 + wn + lr;
#pragma unroll
  for (int nf = 0; nf < 4; nf++) {
    const float bv = bias[cc + nf * 16];
#pragma unroll
    for (int mf = 0; mf < 4; mf++) {
#pragma unroll
      for (int r = 0; r < 4; r++) {
        C[(size_t)(cr + mf * 16 + r) * N + cc + nf * 16] = acc[mf][nf][r] + bv;
      }
    }
  }
}

// Correct-but-slow fallback if workspace is too small (diagnostic path).
__global__ void naive_kernel(const float* __restrict__ x, const int* __restrict__ qweight,
                             const int* __restrict__ qzeros, const float* __restrict__ scales,
                             const float* __restrict__ bias, const int* __restrict__ g_idx,
                             float* __restrict__ out, int in_f, int out_f) {
  const int n = blockIdx.x * blockDim.x + threadIdx.x;
  if (n >= out_f) return;
  const int m = blockIdx.y;
  const float* xr = x + (size_t)m * in_f;
  float acc = 0.f;
  for (int kk = 0; kk < (in_f >> 3); kk++) {
    const int q = qweight[(size_t)kk * out_f + n];
    const int g = g_idx[kk * 8];
    const float s = scales[(size_t)g * out_f + n];
    const int z = (qzeros[(size_t)g * (out_f >> 3) + (n >> 3)] >> ((n & 7) * 4)) & 15;
    float part = 0.f;
#pragma unroll
    for (int j = 0; j < 8; j++)
      part += xr[kk * 8 + j] * (float)(((q >> (4 * j)) & 15) - z);
    acc += s * part;
  }
  out[(size_t)m * out_f + n] = acc + bias[n];
}

extern "C" void kernel_launch(void* const* d_in, const int* in_sizes, int n_in,
                              void* d_out, int out_size, void* d_ws, size_t ws_size,
                              hipStream_t stream) {
  const float* x = (const float*)d_in[0];
  const int* qweight = (const int*)d_in[1];
  const int* qzeros = (const int*)d_in[2];
  const float* scales = (const float*)d_in[3];
  const float* bias = (const float*)d_in[4];
  const int* g_idx = (const int*)d_in[5];
  float* out = (float*)d_out;

  const int out_f = in_sizes[4];          // bias length (N)
  const int in_f = in_sizes[5];           // g_idx length (K)
  const int tokens = in_sizes[0] / in_f;  // x rows (M)

  const size_t need_w = (size_t)in_f * out_f * sizeof(__hip_bfloat16);
  const size_t need_x = (size_t)tokens * in_f * sizeof(__hip_bfloat16);

  if (ws_size >= need_w + need_x && (in_f % 128) == 0 && (out_f % 256) == 0 &&
      (tokens % BM) == 0) {
    __hip_bfloat16* wp = (__hip_bfloat16*)d_ws;
    __hip_bfloat16* xp = (__hip_bfloat16*)((char*)d_ws + need_w);
    dequant_kernel<<<dim3(out_f / 256, in_f / 8), 256, 0, stream>>>(
        qweight, qzeros, scales, wp, out_f, in_f);
    cvtx_kernel<<<dim3(tokens / 64, in_f / 64), 256, 0, stream>>>(x, xp, tokens, in_f);
    gemm_kernel<<<dim3(tokens / BM, out_f / BN), 256, 0, stream>>>(
        xp, wp, bias, out, tokens, out_f, in_f);
  } else {
    naive_kernel<<<dim3((out_f + 255) / 256, tokens), 256, 0, stream>>>(
        x, qweight, qzeros, scales, bias, g_idx, out, in_f, out_f);
  }
}